// Round 3
// baseline (1175.293 us; speedup 1.0000x reference)
//
#include <hip/hip_runtime.h>
#include <cstdint>
#include <cstddef>

#define MAXSEQ 4096
#define NKVH   8
#define NQH    32
#define HDIM   128
#define NB     32
#define NC     32      // sequence chunks for flash-decode
#define CHUNK  128     // MAXSEQ / NC
#define KSPLIT 8

__device__ __forceinline__ float exp2_fast(float x) {
#if __has_builtin(__builtin_amdgcn_exp2f)
  return __builtin_amdgcn_exp2f(x);
#else
  return exp2f(x);
#endif
}

// ---------------------------------------------------------------------------
// GEMM partial: for K-split slice blockIdx.y, computes
//   slab[y][b][r] = sum_{k in slice} A[b][k] * W[r][k]
// A: 32 x 4096 row-major; W row-major N x 4096. Plain stores, no atomics.
// Rows select W0/W1/W2 at boundaries 4096/5120 (qkv fused); for a single
// weight launch with gridDim.x*64 <= 4096.
// LDS odd pad 33 -> compute reads conflict-free.
// ---------------------------------------------------------------------------
__global__ __launch_bounds__(256) void gemm_xwT(
    const float* __restrict__ A,
    const float* __restrict__ W0, const float* __restrict__ W1, const float* __restrict__ W2,
    float* __restrict__ out, int out_stride)
{
  __shared__ float w_lds[64][33];
  __shared__ float x_lds[32][33];
  const int t   = threadIdx.x;
  const int r0  = blockIdx.x * 64;
  const int kc0 = blockIdx.y * 512;

  const float* Wp; int wr0;
  if (r0 < 4096)      { Wp = W0; wr0 = r0; }
  else if (r0 < 5120) { Wp = W1; wr0 = r0 - 4096; }
  else                { Wp = W2; wr0 = r0 - 5120; }

  const int rgrp = t & 31;   // lanes 0..31 distinct rows -> conflict-free
  const int bgrp = t >> 5;   // 0..7 batch group

  float acc[2][4] = {};

  for (int kt = 0; kt < 16; ++kt) {
    const int kb = kc0 + kt * 32;
    // stage W tile 64x32 (512 float4, coalesced)
    #pragma unroll
    for (int jj = 0; jj < 2; ++jj) {
      int f4 = t + jj * 256;
      int row = f4 >> 3, c4 = (f4 & 7) << 2;
      float4 v = *(const float4*)(Wp + (size_t)(wr0 + row) * 4096 + kb + c4);
      w_lds[row][c4]     = v.x; w_lds[row][c4 + 1] = v.y;
      w_lds[row][c4 + 2] = v.z; w_lds[row][c4 + 3] = v.w;
    }
    // stage x tile 32x32 (256 float4)
    {
      int row = t >> 3, c4 = (t & 7) << 2;
      float4 v = *(const float4*)(A + (size_t)row * 4096 + kb + c4);
      x_lds[row][c4]     = v.x; x_lds[row][c4 + 1] = v.y;
      x_lds[row][c4 + 2] = v.z; x_lds[row][c4 + 3] = v.w;
    }
    __syncthreads();
    #pragma unroll 8
    for (int k = 0; k < 32; ++k) {
      float w0 = w_lds[rgrp][k],      w1 = w_lds[rgrp + 32][k];
      float x0 = x_lds[bgrp][k],      x1 = x_lds[bgrp + 8][k];
      float x2 = x_lds[bgrp + 16][k], x3 = x_lds[bgrp + 24][k];
      acc[0][0] += w0 * x0; acc[0][1] += w0 * x1; acc[0][2] += w0 * x2; acc[0][3] += w0 * x3;
      acc[1][0] += w1 * x0; acc[1][1] += w1 * x1; acc[1][2] += w1 * x2; acc[1][3] += w1 * x3;
    }
    __syncthreads();
  }
  float* outp = out + (size_t)blockIdx.y * ((size_t)NB * out_stride);
  #pragma unroll
  for (int i = 0; i < 2; ++i)
    #pragma unroll
    for (int j = 0; j < 4; ++j) {
      int b = bgrp + 8 * j;
      int r = r0 + rgrp + 32 * i;
      outp[(size_t)b * out_stride + r] = acc[i][j];
    }
}

// ---------------------------------------------------------------------------
// Sum KSPLIT slabs of n contiguous floats each -> out. (WO epilogue)
// ---------------------------------------------------------------------------
__global__ __launch_bounds__(256) void reduce_slabs(
    const float* __restrict__ slabs, float* __restrict__ out, int n)
{
  int i = blockIdx.x * 256 + threadIdx.x;
  if (i < n) {
    float s = 0.f;
    #pragma unroll
    for (int j = 0; j < KSPLIT; ++j) s += slabs[(size_t)j * n + i];
    out[i] = s;
  }
}

// ---------------------------------------------------------------------------
// RoPE + scale epilogue. Sums the KSPLIT qkv slabs inline, then:
// rows 0..4095 q -> q_ws (scaled by log2e/sqrt(128)); 4096..5119 k -> rope ->
// cache_k at pos MAXSEQ-1; 5120..6143 v -> copy -> cache_v at pos MAXSEQ-1.
// (Idempotent cache writes; harness restores inputs before each launch.)
// ---------------------------------------------------------------------------
__global__ __launch_bounds__(256) void rope_scatter(
    const float* __restrict__ qkv, const float* __restrict__ fc, const float* __restrict__ fs,
    float* __restrict__ q_ws, float* __restrict__ cache_k, float* __restrict__ cache_v)
{
  const int SLAB = NB * 6144;
  int i = blockIdx.x * 256 + threadIdx.x;   // 32 * 3072 = 98304 pair-slots
  int b = i / 3072, pr = i % 3072;
  const float QSC = 0.08838834764831845f * 1.4426950408889634f;  // log2(e)/sqrt(128)

  int rowoff;                // feature index of the pair (even)
  if (pr < 2048)      rowoff = 2 * pr;            // q region [0,4096)
  else if (pr < 2560) rowoff = 4096 + 2 * (pr - 2048);   // k region
  else                rowoff = 5120 + 2 * (pr - 2560);   // v region

  const float* src = qkv + (size_t)b * 6144 + rowoff;
  float xr = 0.f, xi = 0.f;
  #pragma unroll
  for (int jj = 0; jj < KSPLIT; ++jj) { xr += src[0]; xi += src[1]; src += SLAB; }

  if (pr < 2048) {               // q: 32 heads * 64 pairs
    int p = pr & 63;
    float c = fc[p], s = fs[p];
    float* dst = q_ws + (size_t)b * 4096 + 2 * pr;
    dst[0] = (xr * c - xi * s) * QSC;
    dst[1] = (xr * s + xi * c) * QSC;
  } else if (pr < 2560) {        // k: 8 heads * 64 pairs, rope
    int idx = pr - 2048; int g = idx >> 6, p = idx & 63;
    float c = fc[p], s = fs[p];
    float* dst = cache_k + (((size_t)b * MAXSEQ + (MAXSEQ - 1)) * NKVH + g) * HDIM + 2 * p;
    dst[0] = xr * c - xi * s;
    dst[1] = xr * s + xi * c;
  } else {                       // v: plain copy
    int idx = pr - 2560; int g = idx >> 6, p = idx & 63;
    float* dst = cache_v + (((size_t)b * MAXSEQ + (MAXSEQ - 1)) * NKVH + g) * HDIM + 2 * p;
    dst[0] = xr; dst[1] = xi;
  }
}

// ---------------------------------------------------------------------------
// Flash-decode partials. 8192 wave-jobs = (b, g, chunk); each wave handles 4 q
// heads over CHUNK positions. Each HALF-wave (32 lanes x float4 = 128 dims)
// owns one position stream (even/odd), so the score reduce is a 5-level
// 32-lane butterfly instead of 6-level 64-lane. Defer-max (THR=8) online
// softmax with exp2 (log2e folded into q); half-wave states merged at end.
// ---------------------------------------------------------------------------
__global__ __launch_bounds__(256) void attn_partial(
    const float* __restrict__ cache_k, const float* __restrict__ cache_v,
    const float* __restrict__ q_ws, float* __restrict__ part_o, float* __restrict__ part_ml)
{
  const int lane = threadIdx.x & 63;
  const int half = lane >> 5;        // 0: even positions, 1: odd positions
  const int l32  = lane & 31;        // dims 4*l32 .. 4*l32+3
  const int wid  = threadIdx.x >> 6;
  const int job  = blockIdx.x * 4 + wid;   // 8192 jobs = (b*8+g)*32 + c
  const int b = job >> 8;
  const int g = (job >> 5) & 7;
  const int c = job & 31;

  const size_t kvbase =
      (((size_t)b * MAXSEQ + (size_t)c * CHUNK + half) * NKVH + g) * HDIM + 4 * l32;
  const float* Kp = cache_k + kvbase;
  const float* Vp = cache_v + kvbase;

  float4 q[4];
  #pragma unroll
  for (int h = 0; h < 4; ++h)
    q[h] = *(const float4*)(q_ws + (size_t)b * 4096 + (size_t)(g * 4 + h) * HDIM + 4 * l32);

  float m[4] = {-1e30f, -1e30f, -1e30f, -1e30f};
  float l[4] = {0.f, 0.f, 0.f, 0.f};
  float4 o[4] = {};

  #pragma unroll 4
  for (int i = 0; i < CHUNK / 2; ++i) {
    float4 k4 = *(const float4*)(Kp + (size_t)i * (2 * NKVH * HDIM));
    float4 v4 = *(const float4*)(Vp + (size_t)i * (2 * NKVH * HDIM));
    float p0 = q[0].x * k4.x + q[0].y * k4.y + q[0].z * k4.z + q[0].w * k4.w;
    float p1 = q[1].x * k4.x + q[1].y * k4.y + q[1].z * k4.z + q[1].w * k4.w;
    float p2 = q[2].x * k4.x + q[2].y * k4.y + q[2].z * k4.z + q[2].w * k4.w;
    float p3 = q[3].x * k4.x + q[3].y * k4.y + q[3].z * k4.z + q[3].w * k4.w;
    #pragma unroll
    for (int off = 1; off <= 16; off <<= 1) {
      p0 += __shfl_xor(p0, off);
      p1 += __shfl_xor(p1, off);
      p2 += __shfl_xor(p2, off);
      p3 += __shfl_xor(p3, off);
    }
    // scores now uniform within each half-wave; defer-max online softmax
    float d0 = p0 - m[0], d1 = p1 - m[1], d2 = p2 - m[2], d3 = p3 - m[3];
    float mx = fmaxf(fmaxf(d0, d1), fmaxf(d2, d3));
    if (mx > 8.0f) {
      if (d0 > 8.0f) { float f = exp2_fast(m[0] - p0); m[0] = p0; l[0] *= f;
                       o[0].x *= f; o[0].y *= f; o[0].z *= f; o[0].w *= f; d0 = 0.f; }
      if (d1 > 8.0f) { float f = exp2_fast(m[1] - p1); m[1] = p1; l[1] *= f;
                       o[1].x *= f; o[1].y *= f; o[1].z *= f; o[1].w *= f; d1 = 0.f; }
      if (d2 > 8.0f) { float f = exp2_fast(m[2] - p2); m[2] = p2; l[2] *= f;
                       o[2].x *= f; o[2].y *= f; o[2].z *= f; o[2].w *= f; d2 = 0.f; }
      if (d3 > 8.0f) { float f = exp2_fast(m[3] - p3); m[3] = p3; l[3] *= f;
                       o[3].x *= f; o[3].y *= f; o[3].z *= f; o[3].w *= f; d3 = 0.f; }
    }
    float e0 = exp2_fast(d0), e1 = exp2_fast(d1), e2 = exp2_fast(d2), e3 = exp2_fast(d3);
    l[0] += e0; l[1] += e1; l[2] += e2; l[3] += e3;
    o[0].x += e0 * v4.x; o[0].y += e0 * v4.y; o[0].z += e0 * v4.z; o[0].w += e0 * v4.w;
    o[1].x += e1 * v4.x; o[1].y += e1 * v4.y; o[1].z += e1 * v4.z; o[1].w += e1 * v4.w;
    o[2].x += e2 * v4.x; o[2].y += e2 * v4.y; o[2].z += e2 * v4.z; o[2].w += e2 * v4.w;
    o[3].x += e3 * v4.x; o[3].y += e3 * v4.y; o[3].z += e3 * v4.z; o[3].w += e3 * v4.w;
  }

  // merge even/odd half-wave states per head, then store
  #pragma unroll
  for (int h = 0; h < 4; ++h) {
    float mo = __shfl_xor(m[h], 32);
    float M  = fmaxf(m[h], mo);
    float f  = exp2_fast(m[h] - M);
    float lf = l[h] * f;
    float L  = lf + __shfl_xor(lf, 32);
    float ox = o[h].x * f, oy = o[h].y * f, oz = o[h].z * f, ow = o[h].w * f;
    ox += __shfl_xor(ox, 32); oy += __shfl_xor(oy, 32);
    oz += __shfl_xor(oz, 32); ow += __shfl_xor(ow, 32);
    if (half == 0) {
      float4* dst = (float4*)(part_o + ((size_t)job * 4 + h) * 128 + 4 * l32);
      *dst = make_float4(ox, oy, oz, ow);
      if (l32 == 0) {
        part_ml[((size_t)job * 4 + h) * 2]     = M;
        part_ml[((size_t)job * 4 + h) * 2 + 1] = L;
      }
    }
  }
}

// ---------------------------------------------------------------------------
// Combine NC chunk-partials per (b, g, h) -> ctx[b][(g*4+h)*128 + d]
// ---------------------------------------------------------------------------
__global__ __launch_bounds__(256) void attn_combine(
    const float* __restrict__ part_o, const float* __restrict__ part_ml, float* __restrict__ ctx)
{
  const int t   = threadIdx.x;
  const int job = blockIdx.x * 2 + (t >> 7);   // (b*8+g)*4 + h, 1024 total
  const int d   = t & 127;
  const int bg  = job >> 2;
  const int h   = job & 3;

  float M = -1e30f;
  #pragma unroll 8
  for (int c = 0; c < NC; ++c)
    M = fmaxf(M, part_ml[((size_t)(bg * NC + c) * 4 + h) * 2]);

  float L = 0.f, acc = 0.f;
  #pragma unroll 8
  for (int c = 0; c < NC; ++c) {
    size_t idx = (size_t)(bg * NC + c) * 4 + h;
    float mm = part_ml[idx * 2], ll = part_ml[idx * 2 + 1];
    float f = exp2_fast(mm - M);
    L   += ll * f;
    acc += f * part_o[idx * 128 + d];
  }
  const int b = bg >> 3, g = bg & 7;
  ctx[(size_t)b * 4096 + (size_t)(g * 4 + h) * 128 + d] = acc / L;
}

// ---------------------------------------------------------------------------
extern "C" void kernel_launch(void* const* d_in, const int* in_sizes, int n_in,
                              void* d_out, int out_size, void* d_ws, size_t ws_size,
                              hipStream_t stream)
{
  const float* x  = (const float*)d_in[0];
  float* cache_k  = (float*)d_in[1];   // written at s=4095 (idempotent)
  float* cache_v  = (float*)d_in[2];
  const float* wq = (const float*)d_in[3];
  const float* wk = (const float*)d_in[4];
  const float* wv = (const float*)d_in[5];
  const float* wo = (const float*)d_in[6];
  const float* fc = (const float*)d_in[7];
  const float* fs = (const float*)d_in[8];
  float* out = (float*)d_out;

  char* ws = (char*)d_ws;
  float* qkv_slabs = (float*)(ws);              // 8*32*6144 f32 = 6 MB
  float* q_ws      = (float*)(ws + 6291456);    // 32*4096 f32
  float* ctx       = (float*)(ws + 6815744);    // 32*4096 f32
  float* ctx_slabs = (float*)(ws + 7340032);    // 8*32*4096 f32 = 4 MB
  float* part_ml   = (float*)(ws + 11534336);   // 8192*4*2 f32
  float* part_o    = (float*)(ws + 11796480);   // 8192*4*128 f32 = 16 MB

  // QKV projection (fused wq/wk/wv row ranges), K-split 8 -> slabs
  gemm_xwT<<<dim3(96, 8), 256, 0, stream>>>(x, wq, wk, wv, qkv_slabs, 6144);
  // Slab-sum + RoPE + scale, scatter new k/v into caches
  rope_scatter<<<384, 256, 0, stream>>>(qkv_slabs, fc, fs, q_ws, cache_k, cache_v);
  // Flash-decode partials over 32 chunks
  attn_partial<<<2048, 256, 0, stream>>>(cache_k, cache_v, q_ws, part_o, part_ml);
  attn_combine<<<512, 256, 0, stream>>>(part_o, part_ml, ctx);
  // Output projection, K-split 8 -> slabs, then reduce into d_out
  gemm_xwT<<<dim3(64, 8), 256, 0, stream>>>(ctx, wo, wo, wo, ctx_slabs, 4096);
  reduce_slabs<<<512, 256, 0, stream>>>(ctx_slabs, out, NB * NQH * HDIM);
}